// Round 6
// baseline (1216.190 us; speedup 1.0000x reference)
//
#include <hip/hip_runtime.h>
#include <hip/hip_bf16.h>

#define V  32000
#define HD 512
#define BB 32
#define TT 128
#define VH 32512   // V + HD
#define LBLK 8     // lstm blocks
#define NBLK 256   // total co-resident blocks (1 per CU)
#define GBLK (NBLK - LBLK)
#define NTILE (16 * 125)   // gemm tiles: 4096/256 x 32000/256

typedef short  short8  __attribute__((ext_vector_type(8)));
typedef unsigned short u16x8 __attribute__((ext_vector_type(8)));
typedef unsigned short u16x4 __attribute__((ext_vector_type(4)));
typedef float  f32x4   __attribute__((ext_vector_type(4)));

__device__ __forceinline__ unsigned short bf16_rne(float f) {
  unsigned u = __builtin_bit_cast(unsigned, f);
  u += 0x7FFFu + ((u >> 16) & 1u);
  return (unsigned short)(u >> 16);
}

__device__ __forceinline__ void gload_lds16(const void* g, void* l) {
  __builtin_amdgcn_global_load_lds((const __attribute__((address_space(1))) void*)g,
                                   (__attribute__((address_space(3))) void*)l, 16, 0, 0);
}

__device__ __forceinline__ float sigf(float x) {
  return 1.0f / (1.0f + __expf(-x));
}
__device__ __forceinline__ float tanhf_fast(float x) {
  return 1.0f - 2.0f / (1.0f + __expf(2.0f * x));
}

// ---------------------------------------------------------------------------
// Fused cooperative kernel: 256 blocks x 512 threads (1 per CU).
//   lstm blocks  = {0,8,...,56} (same blkid%8 residue -> typically one XCD;
//                  correctness uses agent-scope fences, placement-independent).
//                  Weights register-resident; per-step barrier on `bar`;
//                  per-step E-availability gate on eflag[t] (2 arrivals).
//   other blocks : gather E chunk-halves (2 blocks per t, flags), convert
//                  Wyb (grid-stride, wbar), then persistent 256x256 GEMM
//                  tiles gated by bar2 (needs t >= 8*bm+8).
// Y written with non-temporal stores (write-once stream).
// ---------------------------------------------------------------------------
__global__ void __launch_bounds__(512, 1) fused_all(
    const int* __restrict__ X,
    const float* __restrict__ Hin,
    const float* __restrict__ Cin,
    const float* __restrict__ Wf, const float* __restrict__ bfp,
    const float* __restrict__ Wi, const float* __restrict__ bip,
    const float* __restrict__ Wo, const float* __restrict__ bop,
    const float* __restrict__ Wc, const float* __restrict__ bcp,
    const float* __restrict__ Wy, const float* __restrict__ by,
    float* __restrict__ E,
    unsigned short* __restrict__ HsM1,   // [-1..127][32][512] bf16
    unsigned short* __restrict__ Wyb,    // [32000][512] bf16
    float* __restrict__ outHC,
    unsigned* __restrict__ bar,          // lstm barrier counter
    unsigned* __restrict__ bar2,         // lstm progress flag
    unsigned* __restrict__ wbar,         // Wyb-convert arrivals
    unsigned* __restrict__ eflag,        // [TT] gather completion (2 each)
    float* __restrict__ Y)
{
  __shared__ __align__(16) char smem[75776];

  const int tid = threadIdx.x;
  const int blkid = blockIdx.x;
  const int wid = tid >> 6, lane = tid & 63;
  const int fr = lane & 15, ko = lane >> 4;

  unsigned short* Hs = HsM1 + BB * HD;

  if (blkid < 64 && (blkid & 7) == 0) {
    // =======================  LSTM role  =======================
    short* hl = (short*)smem;                                   // 32768 B
    float (*Pl)[BB][68] = (float(*)[BB][68])(smem + 32768);     // 34816 B
    float (*cl)[64]     = (float(*)[64])(smem + 32768 + 34816); // 8192 B

    const int blk = blkid >> 3;   // 0..7
    const int g = wid & 3, qg = wid >> 2;

    // ---- one-time: weight fragments into registers (B-frag of 16x16x32) ----
    const float* Wg = (g == 0) ? Wf : (g == 1) ? Wi : (g == 2) ? Wo : Wc;
    short8 wreg[2][16];
    #pragma unroll
    for (int n = 0; n < 2; ++n) {
      const int q = blk * 64 + qg * 32 + n * 16 + fr;
      const float* rowp = Wg + (size_t)q * VH + V;
      #pragma unroll
      for (int kk = 0; kk < 16; ++kk) {
        const float4 lo = *(const float4*)(rowp + kk * 32 + ko * 8);
        const float4 hi = *(const float4*)(rowp + kk * 32 + ko * 8 + 4);
        short8 w;
        w[0] = (short)bf16_rne(lo.x); w[1] = (short)bf16_rne(lo.y);
        w[2] = (short)bf16_rne(lo.z); w[3] = (short)bf16_rne(lo.w);
        w[4] = (short)bf16_rne(hi.x); w[5] = (short)bf16_rne(hi.y);
        w[6] = (short)bf16_rne(hi.z); w[7] = (short)bf16_rne(hi.w);
        wreg[n][kk] = w;
      }
    }

    // ---- cell-state init + h_init bf16 conversion for own q-slice ----
    const int e0 = tid * 4;
    const int eb = e0 >> 6, ql = e0 & 63;
    const int qglob = blk * 64 + ql;
    {
      const f32x4 c4 = *(const f32x4*)(Cin + eb * HD + qglob);
      *(f32x4*)&cl[eb][ql] = c4;
      const f32x4 h4 = *(const f32x4*)(Hin + eb * HD + qglob);
      u16x4 hq;
      #pragma unroll
      for (int j = 0; j < 4; ++j) hq[j] = bf16_rne(h4[j]);
      *(u16x4*)(HsM1 + (size_t)eb * HD + qglob) = hq;
    }
    __syncthreads();

    // ---- prologue barrier: all 8 lstm blocks wrote h_init; E[0] gathered ----
    if (tid == 0) {
      __threadfence();
      __hip_atomic_fetch_add(bar, 1u, __ATOMIC_RELAXED, __HIP_MEMORY_SCOPE_AGENT);
      while (__hip_atomic_load(bar, __ATOMIC_RELAXED, __HIP_MEMORY_SCOPE_AGENT) < (unsigned)LBLK) {}
      while (__hip_atomic_load(&eflag[0], __ATOMIC_RELAXED, __HIP_MEMORY_SCOPE_AGENT) < 2u) {}
      __threadfence();
    }
    __syncthreads();

    int abase[2], asw[2];
    #pragma unroll
    for (int m = 0; m < 2; ++m) {
      const int r = m * 16 + fr;
      abase[m] = r * 1024;
      asw[m] = (r & 7) << 4;
    }

    for (int t = 0; t < TT; ++t) {
      if (t > 0) {
        __syncthreads();   // all Hs[t-1] stores issued & drained
        if (tid == 0) {
          __threadfence();  // release own h stores
          __hip_atomic_fetch_add(bar, 1u, __ATOMIC_RELAXED, __HIP_MEMORY_SCOPE_AGENT);
          const unsigned tgt = (unsigned)(LBLK * (t + 1));
          while (__hip_atomic_load(bar, __ATOMIC_RELAXED, __HIP_MEMORY_SCOPE_AGENT) < tgt) {}
          while (__hip_atomic_load(&eflag[t], __ATOMIC_RELAXED, __HIP_MEMORY_SCOPE_AGENT) < 2u) {}
          __threadfence();  // acquire peers' h + E[t]
          if (blk == 0)
            __hip_atomic_store(bar2, (unsigned)t, __ATOMIC_RELAXED, __HIP_MEMORY_SCOPE_AGENT);
        }
        __syncthreads();
      }

      // stage h_{t-1} (32KB bf16) into LDS, XOR-swizzled via source
      const char* hsrc = (const char*)(HsM1 + (size_t)t * (BB * HD));
      #pragma unroll
      for (int is = 0; is < 4; ++is) {
        const int i = is * 512 + tid;
        const int sb = (i >> 6) * 1024 + (((i & 63) * 16) ^ (((i >> 6) & 7) << 4));
        gload_lds16(hsrc + sb, (char*)hl + (size_t)(is * 512 + (tid & ~63)) * 16);
      }

      // E[t] loads (latency hides under staging drain + MFMA issue)
      const float* Eb = E + ((size_t)t * 4) * BB * HD;
      const f32x4 ef = *(const f32x4*)(Eb + (size_t)(0 * BB + eb) * HD + qglob);
      const f32x4 ei = *(const f32x4*)(Eb + (size_t)(1 * BB + eb) * HD + qglob);
      const f32x4 eo = *(const f32x4*)(Eb + (size_t)(2 * BB + eb) * HD + qglob);
      const f32x4 ec = *(const f32x4*)(Eb + (size_t)(3 * BB + eb) * HD + qglob);

      __syncthreads();   // h_lds ready

      f32x4 acc[2][2];
      #pragma unroll
      for (int m = 0; m < 2; ++m)
        #pragma unroll
        for (int n = 0; n < 2; ++n)
          acc[m][n] = (f32x4){0.f, 0.f, 0.f, 0.f};

      #pragma unroll
      for (int kk = 0; kk < 16; ++kk) {
        const int off = kk * 64 + ko * 16;
        const short8 a0 = *(const short8*)((const char*)hl + abase[0] + (off ^ asw[0]));
        const short8 a1 = *(const short8*)((const char*)hl + abase[1] + (off ^ asw[1]));
        acc[0][0] = __builtin_amdgcn_mfma_f32_16x16x32_bf16(a0, wreg[0][kk], acc[0][0], 0, 0, 0);
        acc[1][0] = __builtin_amdgcn_mfma_f32_16x16x32_bf16(a1, wreg[0][kk], acc[1][0], 0, 0, 0);
        acc[0][1] = __builtin_amdgcn_mfma_f32_16x16x32_bf16(a0, wreg[1][kk], acc[0][1], 0, 0, 0);
        acc[1][1] = __builtin_amdgcn_mfma_f32_16x16x32_bf16(a1, wreg[1][kk], acc[1][1], 0, 0, 0);
      }

      #pragma unroll
      for (int m = 0; m < 2; ++m)
        #pragma unroll
        for (int n = 0; n < 2; ++n)
          #pragma unroll
          for (int j = 0; j < 4; ++j)
            Pl[g][m * 16 + ko * 4 + j][qg * 32 + n * 16 + fr] = acc[m][n][j];
      __syncthreads();

      const f32x4 pf4 = *(const f32x4*)&Pl[0][eb][ql];
      const f32x4 pi4 = *(const f32x4*)&Pl[1][eb][ql];
      const f32x4 po4 = *(const f32x4*)&Pl[2][eb][ql];
      const f32x4 pc4 = *(const f32x4*)&Pl[3][eb][ql];
      const f32x4 cold = *(const f32x4*)&cl[eb][ql];
      f32x4 cnew, hnew;
      u16x4 hq;
      #pragma unroll
      for (int j = 0; j < 4; ++j) {
        const float fg = sigf(pf4[j] + ef[j]);
        const float ig = sigf(pi4[j] + ei[j]);
        const float og = sigf(po4[j] + eo[j]);
        const float ct = tanhf_fast(pc4[j] + ec[j]);
        const float cn = fg * cold[j] + ig * ct;
        const float hv = og * tanhf_fast(cn);
        cnew[j] = cn;
        hnew[j] = hv;
        hq[j] = bf16_rne(hv);
      }
      *(f32x4*)&cl[eb][ql] = cnew;
      *(u16x4*)(Hs + ((size_t)t * BB + eb) * HD + qglob) = hq;
      if (t == TT - 1) {
        *(f32x4*)(outHC + (size_t)eb * HD + qglob) = hnew;
        *(f32x4*)(outHC + (size_t)BB * HD + (size_t)eb * HD + qglob) = cnew;
      }
    }

    // epilogue: publish final step
    __syncthreads();
    if (tid == 0) {
      __threadfence();
      __hip_atomic_fetch_add(bar, 1u, __ATOMIC_RELAXED, __HIP_MEMORY_SCOPE_AGENT);
      if (blk == 0) {
        while (__hip_atomic_load(bar, __ATOMIC_RELAXED, __HIP_MEMORY_SCOPE_AGENT) < (unsigned)(LBLK * (TT + 1))) {}
        __threadfence();
        __hip_atomic_store(bar2, (unsigned)TT, __ATOMIC_RELAXED, __HIP_MEMORY_SCOPE_AGENT);
      }
    }
  } else {
    // =======================  GEMM role  =======================
    unsigned short* As = (unsigned short*)smem;             // 256x64 = 32768 B
    unsigned short* Bs = (unsigned short*)(smem + 32768);   // 256x64 = 32768 B
    int* xs            = (int*)(smem + 65536);              // 64 B

    const int gid = (blkid < 64) ? (blkid - (blkid >> 3) - 1) : (blkid - 8);

    // ---- prologue 1: gather E half-chunks (unit u = t*2 + half) ----
    #pragma unroll
    for (int rep = 0; rep < 2; ++rep) {
      const int u = gid + rep * GBLK;
      if (u < 2 * TT) {
        const int tg = u >> 1, half = u & 1;
        if (tid < 16) xs[tid] = X[(half * 16 + tid) * TT + tg];
        __syncthreads();
        const int q = tid;
        float* Erow = E + ((size_t)tg * 4) * BB * HD;
        #pragma unroll
        for (int g = 0; g < 4; ++g) {
          const float* W = (g == 0) ? Wf : (g == 1) ? Wi : (g == 2) ? Wo : Wc;
          const float* bsrc = (g == 0) ? bfp : (g == 1) ? bip : (g == 2) ? bop : bcp;
          const float bias = bsrc[q];
          const float* wq = W + (size_t)q * VH;
          #pragma unroll 4
          for (int b = 0; b < 16; ++b) {
            const float v = __builtin_nontemporal_load(wq + xs[b]);
            Erow[(size_t)(g * BB + half * 16 + b) * HD + q] = v + bias;
          }
        }
        __syncthreads();
        if (tid == 0) {
          __threadfence();  // release gathered E half
          __hip_atomic_fetch_add(&eflag[tg], 1u, __ATOMIC_RELAXED, __HIP_MEMORY_SCOPE_AGENT);
        }
      }
    }

    // ---- prologue 2: convert Wy -> Wyb (grid-stride over GEMM blocks) ----
    {
      const size_t n = (size_t)V * HD;
      for (size_t i = ((size_t)gid * 512 + tid) * 8; i < n;
           i += (size_t)GBLK * 512 * 8) {
        const f32x4 a = __builtin_nontemporal_load((const f32x4*)(Wy + i));
        const f32x4 b = __builtin_nontemporal_load((const f32x4*)(Wy + i + 4));
        u16x8 o;
        o[0] = bf16_rne(a[0]); o[1] = bf16_rne(a[1]); o[2] = bf16_rne(a[2]); o[3] = bf16_rne(a[3]);
        o[4] = bf16_rne(b[0]); o[5] = bf16_rne(b[1]); o[6] = bf16_rne(b[2]); o[7] = bf16_rne(b[3]);
        *(u16x8*)(Wyb + i) = o;
      }
      __syncthreads();
      if (tid == 0) {
        __threadfence();  // release Wyb slice
        __hip_atomic_fetch_add(wbar, 1u, __ATOMIC_RELAXED, __HIP_MEMORY_SCOPE_AGENT);
        while (__hip_atomic_load(wbar, __ATOMIC_RELAXED, __HIP_MEMORY_SCOPE_AGENT) < (unsigned)GBLK)
          __builtin_amdgcn_s_sleep(2);
        __threadfence();  // acquire full Wyb
      }
      __syncthreads();
    }

    const int wr = wid >> 2, wc = wid & 3;   // 2 x 4 wave grid, each 128x64 out

    for (int tile = gid; tile < NTILE; tile += GBLK) {
      const int bm = tile / 125, bn = tile % 125;
      const int row0 = bm << 8, col0 = bn << 8;

      // wait until Hs rows row0..row0+255 (steps 8bm..8bm+7) are published
      if (tid == 0) {
        const unsigned need = (unsigned)(8 * bm + 8);
        while (__hip_atomic_load(bar2, __ATOMIC_RELAXED, __HIP_MEMORY_SCOPE_AGENT) < need)
          __builtin_amdgcn_s_sleep(2);
        __threadfence();  // acquire Hs
      }
      __syncthreads();

      f32x4 acc[8][4];
      #pragma unroll
      for (int m = 0; m < 8; ++m)
        #pragma unroll
        for (int n = 0; n < 4; ++n)
          acc[m][n] = (f32x4){0.f, 0.f, 0.f, 0.f};

      for (int kt = 0; kt < 8; ++kt) {
        const int k0 = kt << 6;
        #pragma unroll
        for (int is = 0; is < 4; ++is) {
          const int id = is * 512 + tid;
          const int r = id >> 3;
          const int c = (id & 7) ^ (r & 7);
          gload_lds16(Hs + (size_t)(row0 + r) * 512 + k0 + c * 8,
                      &As[(is * 512 + (tid & ~63)) * 8]);
        }
        #pragma unroll
        for (int is = 0; is < 4; ++is) {
          const int id = is * 512 + tid;
          const int r = id >> 3;
          const int c = (id & 7) ^ (r & 7);
          gload_lds16(Wyb + (size_t)(col0 + r) * 512 + k0 + c * 8,
                      &Bs[(is * 512 + (tid & ~63)) * 8]);
        }
        __syncthreads();
        #pragma unroll
        for (int kk = 0; kk < 2; ++kk) {
          const int K = (kk << 2) | ko;
          short8 af[8], bfr[4];
          #pragma unroll
          for (int m = 0; m < 8; ++m) {
            const int r = (wr << 7) + (m << 4) + fr;
            af[m] = *(const short8*)((const char*)As + r * 128 + ((K ^ (r & 7)) << 4));
          }
          #pragma unroll
          for (int n = 0; n < 4; ++n) {
            const int r = (wc << 6) + (n << 4) + fr;
            bfr[n] = *(const short8*)((const char*)Bs + r * 128 + ((K ^ (r & 7)) << 4));
          }
          #pragma unroll
          for (int m = 0; m < 8; ++m)
            #pragma unroll
            for (int n = 0; n < 4; ++n)
              acc[m][n] = __builtin_amdgcn_mfma_f32_16x16x32_bf16(
                  af[m], bfr[n], acc[m][n], 0, 0, 0);
        }
        __syncthreads();
      }

      const int rgrp = lane >> 4;
      #pragma unroll
      for (int n = 0; n < 4; ++n) {
        const int col = col0 + (wc << 6) + (n << 4) + fr;
        const float bias = by[col];
        #pragma unroll
        for (int m = 0; m < 8; ++m) {
          const int rowb = row0 + (wr << 7) + (m << 4) + (rgrp << 2);
          #pragma unroll
          for (int j = 0; j < 4; ++j) {
            __builtin_nontemporal_store(acc[m][n][j] + bias,
                                        &Y[(size_t)(rowb + j) * V + col]);
          }
        }
      }
    }
  }
}

// ---------------------------------------------------------------------------
extern "C" void kernel_launch(void* const* d_in, const int* in_sizes, int n_in,
                              void* d_out, int out_size, void* d_ws, size_t ws_size,
                              hipStream_t stream)
{
  const int*   X  = (const int*)  d_in[0];
  const float* H  = (const float*)d_in[1];
  const float* C  = (const float*)d_in[2];
  const float* Wf = (const float*)d_in[3];
  const float* bf = (const float*)d_in[4];
  const float* Wi = (const float*)d_in[5];
  const float* bi = (const float*)d_in[6];
  const float* Wo = (const float*)d_in[7];
  const float* bo = (const float*)d_in[8];
  const float* Wc = (const float*)d_in[9];
  const float* bc = (const float*)d_in[10];
  const float* Wy = (const float*)d_in[11];
  const float* by = (const float*)d_in[12];

  float* Y = (float*)d_out;
  float* outHC = Y + (size_t)TT * BB * V;

  char* ws = (char*)d_ws;
  float* E              = (float*)ws;                               // 33,554,432 B
  unsigned short* Wyb   = (unsigned short*)(ws + 33554432);         // 32,768,000 B
  unsigned short* HsM1  = (unsigned short*)(ws + 66322432);         // 32,768 + 4,194,304 B
  unsigned* bar         = (unsigned*)(ws + 70549504);               // +0
  unsigned* bar2        = (unsigned*)(ws + 70549504 + 64);          // +64
  unsigned* wbar        = (unsigned*)(ws + 70549504 + 128);         // +128
  unsigned* eflag       = (unsigned*)(ws + 70549504 + 256);         // +256, 512 B

  (void)hipMemsetAsync(bar, 0, 1024, stream);

  {
    const int* X_p = X;
    const float *H_p = H, *C_p = C;
    const float *Wf_p = Wf, *bf_p = bf, *Wi_p = Wi, *bi_p = bi;
    const float *Wo_p = Wo, *bo_p = bo, *Wc_p = Wc, *bc_p = bc;
    const float *Wy_p = Wy, *by_p = by;
    float* E_p = E;
    unsigned short* HsM1_p = HsM1;
    unsigned short* Wyb_p = Wyb;
    float* outHC_p = outHC;
    unsigned *bar_p = bar, *bar2_p = bar2, *wbar_p = wbar, *eflag_p = eflag;
    float* Y_p = Y;
    void* args[] = {(void*)&X_p, (void*)&H_p, (void*)&C_p,
                    (void*)&Wf_p, (void*)&bf_p, (void*)&Wi_p, (void*)&bi_p,
                    (void*)&Wo_p, (void*)&bo_p, (void*)&Wc_p, (void*)&bc_p,
                    (void*)&Wy_p, (void*)&by_p,
                    (void*)&E_p, (void*)&HsM1_p, (void*)&Wyb_p, (void*)&outHC_p,
                    (void*)&bar_p, (void*)&bar2_p, (void*)&wbar_p, (void*)&eflag_p,
                    (void*)&Y_p};
    (void)hipLaunchCooperativeKernel((void*)fused_all, dim3(NBLK), dim3(512), args, 0, stream);
  }
}

// Round 7
// 900.311 us; speedup vs baseline: 1.3509x; 1.3509x over previous
//
#include <hip/hip_runtime.h>
#include <hip/hip_bf16.h>

#define V  32000
#define HD 512
#define BB 32
#define TT 128
#define VH 32512   // V + HD
#define LBLK 8     // lstm blocks (co-XCD, weights register-resident)
#define NBLK 256   // total co-resident blocks (1 per CU)
#define GBLK (NBLK - LBLK)
#define NTILE (32 * 125)   // gemm tiles: 4096/128 x 32000/256

typedef short  short8  __attribute__((ext_vector_type(8)));
typedef unsigned short u16x8 __attribute__((ext_vector_type(8)));
typedef unsigned short u16x4 __attribute__((ext_vector_type(4)));
typedef float  f32x4   __attribute__((ext_vector_type(4)));

__device__ __forceinline__ unsigned short bf16_rne(float f) {
  unsigned u = __builtin_bit_cast(unsigned, f);
  u += 0x7FFFu + ((u >> 16) & 1u);
  return (unsigned short)(u >> 16);
}

__device__ __forceinline__ void gload_lds16(const void* g, void* l) {
  __builtin_amdgcn_global_load_lds((const __attribute__((address_space(1))) void*)g,
                                   (__attribute__((address_space(3))) void*)l, 16, 0, 0);
}

__device__ __forceinline__ float sigf(float x) {
  return 1.0f / (1.0f + __expf(-x));
}
__device__ __forceinline__ float tanhf_fast(float x) {
  return 1.0f - 2.0f / (1.0f + __expf(2.0f * x));
}

__device__ __forceinline__ unsigned aload(const unsigned* p) {
  return __hip_atomic_load(p, __ATOMIC_RELAXED, __HIP_MEMORY_SCOPE_AGENT);
}
__device__ __forceinline__ void astore(unsigned* p, unsigned v) {
  __hip_atomic_store(p, v, __ATOMIC_RELAXED, __HIP_MEMORY_SCOPE_AGENT);
}
__device__ __forceinline__ unsigned aadd(unsigned* p, unsigned v) {
  return __hip_atomic_fetch_add(p, v, __ATOMIC_RELAXED, __HIP_MEMORY_SCOPE_AGENT);
}

// ---------------------------------------------------------------------------
// Fused cooperative kernel: 256 blocks x 512 threads (1 per CU).
// Roles claimed at runtime: first 8 blocks on XCD 0 (s_getreg XCC_ID) become
// the LSTM; everyone else GEMM. Single-writer monotonic-flag sync:
//   - lstm h-exchange: co-XCD shared L2, no fences (vmcnt drain via
//     __syncthreads is the release; first-touch reads can't be stale).
//   - Hs -> GEMM (cross-XCD): block0 does ONE threadfence (wbl2) per 8 steps
//     before publishing bar2 (GEMM gates at 8-step granularity).
//   - E[t]: gather producer does threadfence + eflag[t] (cross-XCD publish);
//     lstm consumer gates on eflag[t], reads are first-touch (no acquire).
//   - GEMM tiles: NO per-tile fences (Wyb/Hs stay L2-resident).
// Y written with non-temporal stores.
// ---------------------------------------------------------------------------
__global__ void __launch_bounds__(512, 2) fused_all(
    const int* __restrict__ X,
    const float* __restrict__ Hin,
    const float* __restrict__ Cin,
    const float* __restrict__ Wf, const float* __restrict__ bfp,
    const float* __restrict__ Wi, const float* __restrict__ bip,
    const float* __restrict__ Wo, const float* __restrict__ bop,
    const float* __restrict__ Wc, const float* __restrict__ bcp,
    const float* __restrict__ Wy, const float* __restrict__ by,
    float* __restrict__ E,
    unsigned short* __restrict__ HsM1,   // [-1..127][32][512] bf16
    unsigned short* __restrict__ Wyb,    // [32000][512] bf16
    float* __restrict__ outHC,
    unsigned* __restrict__ bar,          // lstm barrier counter
    unsigned* __restrict__ bar2,         // lstm progress flag (for GEMM)
    unsigned* __restrict__ wbar,         // Wyb-convert arrivals
    unsigned* __restrict__ eflag,        // [TT] per-chunk gather flags
    unsigned* __restrict__ lticket,      // lstm role tickets (XCD0 only)
    unsigned* __restrict__ gticket,      // gemm role tickets
    float* __restrict__ Y)
{
  __shared__ __align__(16) char smem[75776];
  __shared__ int sh_role;

  const int tid = threadIdx.x;
  const int wid = tid >> 6, lane = tid & 63;
  const int fr = lane & 15, ko = lane >> 4;

  unsigned short* Hs = HsM1 + BB * HD;

  // ---- runtime role claim: first LBLK blocks on XCD 0 become LSTM ----
  if (tid == 0) {
    unsigned xcd;
    asm volatile("s_getreg_b32 %0, hwreg(20, 0, 32)" : "=s"(xcd));  // HW_REG_XCC_ID
    int role = -1;
    if (xcd == 0) {
      const unsigned s = aadd(lticket, 1u);
      if (s < (unsigned)LBLK) role = (int)s;
    }
    if (role < 0) {
      const unsigned g = aadd(gticket, 1u);
      role = -(int)g - 2;   // gemm id encoded as -(gid)-2
    }
    sh_role = role;
  }
  __syncthreads();
  const int role = sh_role;

  if (role >= 0) {
    // =======================  LSTM role  =======================
    short* hl = (short*)smem;                                   // 32768 B
    float (*Pl)[BB][68] = (float(*)[BB][68])(smem + 32768);     // 34816 B
    float (*cl)[64]     = (float(*)[64])(smem + 32768 + 34816); // 8192 B

    const int blk = role;                 // 0..7, q-slice = blk*64
    const int g = wid & 3, qg = wid >> 2;

    // ---- one-time: weight fragments into registers (B-frag of 16x16x32) ----
    const float* Wg = (g == 0) ? Wf : (g == 1) ? Wi : (g == 2) ? Wo : Wc;
    short8 wreg[2][16];
    #pragma unroll
    for (int n = 0; n < 2; ++n) {
      const int q = blk * 64 + qg * 32 + n * 16 + fr;
      const float* rowp = Wg + (size_t)q * VH + V;
      #pragma unroll
      for (int kk = 0; kk < 16; ++kk) {
        const float4 lo = *(const float4*)(rowp + kk * 32 + ko * 8);
        const float4 hi = *(const float4*)(rowp + kk * 32 + ko * 8 + 4);
        short8 w;
        w[0] = (short)bf16_rne(lo.x); w[1] = (short)bf16_rne(lo.y);
        w[2] = (short)bf16_rne(lo.z); w[3] = (short)bf16_rne(lo.w);
        w[4] = (short)bf16_rne(hi.x); w[5] = (short)bf16_rne(hi.y);
        w[6] = (short)bf16_rne(hi.z); w[7] = (short)bf16_rne(hi.w);
        wreg[n][kk] = w;
      }
    }

    // ---- cell-state init + h_init bf16 conversion for own q-slice ----
    const int e0 = tid * 4;
    const int eb = e0 >> 6, ql = e0 & 63;
    const int qglob = blk * 64 + ql;
    {
      const f32x4 c4 = *(const f32x4*)(Cin + eb * HD + qglob);
      *(f32x4*)&cl[eb][ql] = c4;
      const f32x4 h4 = *(const f32x4*)(Hin + eb * HD + qglob);
      u16x4 hq;
      #pragma unroll
      for (int j = 0; j < 4; ++j) hq[j] = bf16_rne(h4[j]);
      *(u16x4*)(HsM1 + (size_t)eb * HD + qglob) = hq;
    }
    __syncthreads();   // drains vmcnt: h_init complete in (shared) L2

    // ---- prologue barrier: all lstm blocks arrived + E[0] published ----
    if (tid == 0) {
      aadd(bar, 1u);
      while (aload(bar) < (unsigned)LBLK) {}
      while (aload(&eflag[0]) < 1u) {}
    }
    __syncthreads();

    int abase[2], asw[2];
    #pragma unroll
    for (int m = 0; m < 2; ++m) {
      const int r = m * 16 + fr;
      abase[m] = r * 1024;
      asw[m] = (r & 7) << 4;
    }

    for (int t = 0; t < TT; ++t) {
      if (t > 0) {
        __syncthreads();   // all Hs[t-1] stores complete in shared L2
        if (tid == 0) {
          aadd(bar, 1u);
          const unsigned tgt = (unsigned)(LBLK * (t + 1));
          while (aload(bar) < tgt) {}
          while (aload(&eflag[t]) < 1u) {}
          if (blk == 0 && (t & 7) == 0) {
            __threadfence();           // wbl2: flush XCD0 L2 (all h lines)
            astore(bar2, (unsigned)t); // publish steps 0..t-1 to GEMM
          }
        }
        __syncthreads();
      }

      // stage h_{t-1} (32KB bf16) into LDS, XOR-swizzled via source.
      // Reads hit the shared XCD0 L2 (peers' stores) - first-touch, no fence.
      const char* hsrc = (const char*)(HsM1 + (size_t)t * (BB * HD));
      #pragma unroll
      for (int is = 0; is < 4; ++is) {
        const int i = is * 512 + tid;
        const int sb = (i >> 6) * 1024 + (((i & 63) * 16) ^ (((i >> 6) & 7) << 4));
        gload_lds16(hsrc + sb, (char*)hl + (size_t)(is * 512 + (tid & ~63)) * 16);
      }

      // E[t] loads (gated by eflag[t]; latency hides under staging + MFMA)
      const float* Eb = E + ((size_t)t * 4) * BB * HD;
      const f32x4 ef = *(const f32x4*)(Eb + (size_t)(0 * BB + eb) * HD + qglob);
      const f32x4 ei = *(const f32x4*)(Eb + (size_t)(1 * BB + eb) * HD + qglob);
      const f32x4 eo = *(const f32x4*)(Eb + (size_t)(2 * BB + eb) * HD + qglob);
      const f32x4 ec = *(const f32x4*)(Eb + (size_t)(3 * BB + eb) * HD + qglob);

      __syncthreads();   // h_lds ready

      f32x4 acc[2][2];
      #pragma unroll
      for (int m = 0; m < 2; ++m)
        #pragma unroll
        for (int n = 0; n < 2; ++n)
          acc[m][n] = (f32x4){0.f, 0.f, 0.f, 0.f};

      #pragma unroll
      for (int kk = 0; kk < 16; ++kk) {
        const int off = kk * 64 + ko * 16;
        const short8 a0 = *(const short8*)((const char*)hl + abase[0] + (off ^ asw[0]));
        const short8 a1 = *(const short8*)((const char*)hl + abase[1] + (off ^ asw[1]));
        acc[0][0] = __builtin_amdgcn_mfma_f32_16x16x32_bf16(a0, wreg[0][kk], acc[0][0], 0, 0, 0);
        acc[1][0] = __builtin_amdgcn_mfma_f32_16x16x32_bf16(a1, wreg[0][kk], acc[1][0], 0, 0, 0);
        acc[0][1] = __builtin_amdgcn_mfma_f32_16x16x32_bf16(a0, wreg[1][kk], acc[0][1], 0, 0, 0);
        acc[1][1] = __builtin_amdgcn_mfma_f32_16x16x32_bf16(a1, wreg[1][kk], acc[1][1], 0, 0, 0);
      }

      #pragma unroll
      for (int m = 0; m < 2; ++m)
        #pragma unroll
        for (int n = 0; n < 2; ++n)
          #pragma unroll
          for (int j = 0; j < 4; ++j)
            Pl[g][m * 16 + ko * 4 + j][qg * 32 + n * 16 + fr] = acc[m][n][j];
      __syncthreads();

      const f32x4 pf4 = *(const f32x4*)&Pl[0][eb][ql];
      const f32x4 pi4 = *(const f32x4*)&Pl[1][eb][ql];
      const f32x4 po4 = *(const f32x4*)&Pl[2][eb][ql];
      const f32x4 pc4 = *(const f32x4*)&Pl[3][eb][ql];
      const f32x4 cold = *(const f32x4*)&cl[eb][ql];
      f32x4 cnew, hnew;
      u16x4 hq;
      #pragma unroll
      for (int j = 0; j < 4; ++j) {
        const float fg = sigf(pf4[j] + ef[j]);
        const float ig = sigf(pi4[j] + ei[j]);
        const float og = sigf(po4[j] + eo[j]);
        const float ct = tanhf_fast(pc4[j] + ec[j]);
        const float cn = fg * cold[j] + ig * ct;
        const float hv = og * tanhf_fast(cn);
        cnew[j] = cn;
        hnew[j] = hv;
        hq[j] = bf16_rne(hv);
      }
      *(f32x4*)&cl[eb][ql] = cnew;
      *(u16x4*)(Hs + ((size_t)t * BB + eb) * HD + qglob) = hq;
      if (t == TT - 1) {
        *(f32x4*)(outHC + (size_t)eb * HD + qglob) = hnew;
        *(f32x4*)(outHC + (size_t)BB * HD + (size_t)eb * HD + qglob) = cnew;
      }
    }

    // epilogue: publish final steps (cross-XCD: fence then flag)
    __syncthreads();
    if (tid == 0) {
      aadd(bar, 1u);
      if (blk == 0) {
        while (aload(bar) < (unsigned)(LBLK * (TT + 1))) {}
        __threadfence();   // wbl2: flush last h lines to L3
        astore(bar2, (unsigned)TT);
      }
    }
  } else {
    // =======================  GEMM role  =======================
    unsigned short* As = (unsigned short*)smem;             // 128x64 = 16384 B
    unsigned short* Bs = (unsigned short*)(smem + 16384);   // 256x64 = 32768 B
    int* xs            = (int*)(smem + 49152);              // 128 B

    const int gid = -role - 2;   // 0..GBLK-1

    // ---- prologue 1: gather E chunk t = gid (t < TT) ----
    if (gid < TT) {
      const int tch = gid;
      if (tid < BB) xs[tid] = X[tid * TT + tch];
      __syncthreads();
      const int q = tid;
      float* Erow = E + ((size_t)tch * 4) * BB * HD;
      #pragma unroll
      for (int g = 0; g < 4; ++g) {
        const float* W = (g == 0) ? Wf : (g == 1) ? Wi : (g == 2) ? Wo : Wc;
        const float* bsrc = (g == 0) ? bfp : (g == 1) ? bip : (g == 2) ? bop : bcp;
        const float bias = bsrc[q];
        const float* wq = W + (size_t)q * VH;
        #pragma unroll 4
        for (int b = 0; b < BB; ++b) {
          const float v = __builtin_nontemporal_load(wq + xs[b]);
          Erow[(size_t)(g * BB + b) * HD + q] = v + bias;
        }
      }
      __syncthreads();
      if (tid == 0) {
        __threadfence();            // release gathered E (cross-XCD consumer)
        astore(&eflag[tch], 1u);
      }
    }

    // ---- prologue 2: convert Wy -> Wyb (grid-stride over GEMM blocks) ----
    {
      const size_t n = (size_t)V * HD;
      for (size_t i = ((size_t)gid * 512 + tid) * 8; i < n;
           i += (size_t)GBLK * 512 * 8) {
        const f32x4 a = __builtin_nontemporal_load((const f32x4*)(Wy + i));
        const f32x4 b = __builtin_nontemporal_load((const f32x4*)(Wy + i + 4));
        u16x8 o;
        o[0] = bf16_rne(a[0]); o[1] = bf16_rne(a[1]); o[2] = bf16_rne(a[2]); o[3] = bf16_rne(a[3]);
        o[4] = bf16_rne(b[0]); o[5] = bf16_rne(b[1]); o[6] = bf16_rne(b[2]); o[7] = bf16_rne(b[3]);
        *(u16x8*)(Wyb + i) = o;
      }
      __syncthreads();
      if (tid == 0) {
        __threadfence();   // release own Wyb slice (one-time)
        aadd(wbar, 1u);
        while (aload(wbar) < (unsigned)GBLK)
          __builtin_amdgcn_s_sleep(2);
      }
      __syncthreads();
    }

    const int wr = wid >> 2, wc = wid & 3;   // 2 x 4 wave grid

    for (int tile = gid; tile < NTILE; tile += GBLK) {
      const int bm = tile / 125, bn = tile % 125;
      const int row0 = bm << 7, col0 = bn << 8;

      // wait until Hs rows row0..row0+127 (steps 4bm..4bm+3) are published.
      // No acquire fence: Hs lines are first-touch (gated), Wyb stays L2-hot.
      if (tid == 0) {
        const unsigned need = (unsigned)(4 * bm + 4);
        while (aload(bar2) < need)
          __builtin_amdgcn_s_sleep(2);
      }
      __syncthreads();

      f32x4 acc[4][4];
      #pragma unroll
      for (int m = 0; m < 4; ++m)
        #pragma unroll
        for (int n = 0; n < 4; ++n)
          acc[m][n] = (f32x4){0.f, 0.f, 0.f, 0.f};

      for (int kt = 0; kt < 8; ++kt) {
        const int k0 = kt << 6;
        #pragma unroll
        for (int is = 0; is < 2; ++is) {
          const int id = is * 512 + tid;
          const int r = id >> 3;
          const int c = (id & 7) ^ (r & 7);
          gload_lds16(Hs + (size_t)(row0 + r) * 512 + k0 + c * 8,
                      &As[(is * 512 + (tid & ~63)) * 8]);
        }
        #pragma unroll
        for (int is = 0; is < 4; ++is) {
          const int id = is * 512 + tid;
          const int r = id >> 3;
          const int c = (id & 7) ^ (r & 7);
          gload_lds16(Wyb + (size_t)(col0 + r) * 512 + k0 + c * 8,
                      &Bs[(is * 512 + (tid & ~63)) * 8]);
        }
        __syncthreads();
        #pragma unroll
        for (int kk = 0; kk < 2; ++kk) {
          short8 af[4], bfr[4];
          #pragma unroll
          for (int m = 0; m < 4; ++m) {
            const int r = (wr << 6) + (m << 4) + fr;
            const int c = ((kk << 2) | ko) ^ (r & 7);
            af[m] = *(const short8*)&As[r * 64 + c * 8];
          }
          #pragma unroll
          for (int n = 0; n < 4; ++n) {
            const int r = (wc << 6) + (n << 4) + fr;
            const int c = ((kk << 2) | ko) ^ (r & 7);
            bfr[n] = *(const short8*)&Bs[r * 64 + c * 8];
          }
          #pragma unroll
          for (int m = 0; m < 4; ++m)
            #pragma unroll
            for (int n = 0; n < 4; ++n)
              acc[m][n] = __builtin_amdgcn_mfma_f32_16x16x32_bf16(
                  af[m], bfr[n], acc[m][n], 0, 0, 0);
        }
        __syncthreads();
      }

      const int rgrp = lane >> 4;
      #pragma unroll
      for (int n = 0; n < 4; ++n) {
        const int col = col0 + (wc << 6) + (n << 4) + fr;
        const float bias = by[col];
        #pragma unroll
        for (int m = 0; m < 4; ++m) {
          const int rowb = row0 + (wr << 6) + (m << 4) + (rgrp << 2);
          #pragma unroll
          for (int j = 0; j < 4; ++j) {
            __builtin_nontemporal_store(acc[m][n][j] + bias,
                                        &Y[(size_t)(rowb + j) * V + col]);
          }
        }
      }
    }
  }
}

// ---------------------------------------------------------------------------
extern "C" void kernel_launch(void* const* d_in, const int* in_sizes, int n_in,
                              void* d_out, int out_size, void* d_ws, size_t ws_size,
                              hipStream_t stream)
{
  const int*   X  = (const int*)  d_in[0];
  const float* H  = (const float*)d_in[1];
  const float* C  = (const float*)d_in[2];
  const float* Wf = (const float*)d_in[3];
  const float* bf = (const float*)d_in[4];
  const float* Wi = (const float*)d_in[5];
  const float* bi = (const float*)d_in[6];
  const float* Wo = (const float*)d_in[7];
  const float* bo = (const float*)d_in[8];
  const float* Wc = (const float*)d_in[9];
  const float* bc = (const float*)d_in[10];
  const float* Wy = (const float*)d_in[11];
  const float* by = (const float*)d_in[12];

  float* Y = (float*)d_out;
  float* outHC = Y + (size_t)TT * BB * V;

  char* ws = (char*)d_ws;
  float* E              = (float*)ws;                               // 33,554,432 B
  unsigned short* Wyb   = (unsigned short*)(ws + 33554432);         // 32,768,000 B
  unsigned short* HsM1  = (unsigned short*)(ws + 66322432);         // 32,768 + 4,194,304 B
  unsigned* bar         = (unsigned*)(ws + 70549504);               // +0
  unsigned* bar2        = (unsigned*)(ws + 70549504 + 64);          // +64
  unsigned* wbar        = (unsigned*)(ws + 70549504 + 128);         // +128
  unsigned* lticket     = (unsigned*)(ws + 70549504 + 192);         // +192
  unsigned* gticket     = (unsigned*)(ws + 70549504 + 256);         // +256
  unsigned* eflag       = (unsigned*)(ws + 70549504 + 320);         // +320, 512 B

  (void)hipMemsetAsync(bar, 0, 1024, stream);

  {
    const int* X_p = X;
    const float *H_p = H, *C_p = C;
    const float *Wf_p = Wf, *bf_p = bf, *Wi_p = Wi, *bi_p = bi;
    const float *Wo_p = Wo, *bo_p = bo, *Wc_p = Wc, *bc_p = bc;
    const float *Wy_p = Wy, *by_p = by;
    float* E_p = E;
    unsigned short* HsM1_p = HsM1;
    unsigned short* Wyb_p = Wyb;
    float* outHC_p = outHC;
    unsigned *bar_p = bar, *bar2_p = bar2, *wbar_p = wbar, *eflag_p = eflag;
    unsigned *lticket_p = lticket, *gticket_p = gticket;
    float* Y_p = Y;
    void* args[] = {(void*)&X_p, (void*)&H_p, (void*)&C_p,
                    (void*)&Wf_p, (void*)&bf_p, (void*)&Wi_p, (void*)&bi_p,
                    (void*)&Wo_p, (void*)&bo_p, (void*)&Wc_p, (void*)&bc_p,
                    (void*)&Wy_p, (void*)&by_p,
                    (void*)&E_p, (void*)&HsM1_p, (void*)&Wyb_p, (void*)&outHC_p,
                    (void*)&bar_p, (void*)&bar2_p, (void*)&wbar_p, (void*)&eflag_p,
                    (void*)&lticket_p, (void*)&gticket_p,
                    (void*)&Y_p};
    (void)hipLaunchCooperativeKernel((void*)fused_all, dim3(NBLK), dim3(512), args, 0, stream);
  }
}